// Round 6
// baseline (6312.078 us; speedup 1.0000x reference)
//
#include <hip/hip_runtime.h>
#include <hip/hip_bf16.h>

// Neural ODE Euler rollout, persistent weight-stationary model-parallel kernel.
// B=256, T=128, X=256, H=1024, L=3.
// 4 groups x 64 blocks; group g owns batch rows [64g,64g+64).
// Block j owns 16 H-cols; weights resident in LDS (fragment-major, ~137KB).
// 4 phases/step (E fused into A via Wcomp=Wout@Win). Atomic-free epoch barrier.
//
// Round-6 change (R5 post-mortem: phase time == bypass-broadcast volume / IF$
// BW; sc0 sc1 loads defeat L2 multicast):
//   Panel reads are PLAIN CACHED loads (L2-multicast: first reader per XCD
//   fills L2, ~31 others hit). Coherence via acquire-only agent fence
//   (buffer_inv, NO buffer_wbl2) once per phase inside BAR. L2 is kept CLEAN
//   by construction: every loop-side global store is write-through bypass
//   (activations AT_ST sc0 sc1; out[] via global_store_dword sc0 sc1 --
//   required, buffer_inv would discard dirty lines).

typedef __attribute__((ext_vector_type(8))) short short8;
typedef __attribute__((ext_vector_type(4))) float f32x4;

#define AT_LD(p) __hip_atomic_load((p), __ATOMIC_RELAXED, __HIP_MEMORY_SCOPE_AGENT)
#define AT_ST(p, v) \
  __hip_atomic_store((p), (v), __ATOMIC_RELAXED, __HIP_MEMORY_SCOPE_AGENT)

// Write-through coherent fp32 store (keeps L2 clean; survives buffer_inv).
#define GST_BYPASS(ptr, val) \
  asm volatile("global_store_dword %0, %1, off sc0 sc1" \
               :: "v"(ptr), "v"(val) : "memory")

__device__ inline unsigned short f2bf(float f) {
  unsigned u = __builtin_bit_cast(unsigned, f);
  unsigned r = u + 0x7FFFu + ((u >> 16) & 1u);
  return (unsigned short)(r >> 16);
}

__global__ __launch_bounds__(256, 1) void node_persistent(
    const float* __restrict__ x, const float* __restrict__ ts,
    const float* __restrict__ Win, const float* __restrict__ bin,
    const float* __restrict__ Wh, const float* __restrict__ bh,
    const float* __restrict__ Wout, const float* __restrict__ bout,
    float* __restrict__ out,
    unsigned* __restrict__ cnt,
    unsigned short* __restrict__ a0,
    unsigned short* __restrict__ a1) {
  // LDS: fragment-major slices. Element (k,c) -> ((k>>3)*16 + c)*8 + (k&7)
  alignas(16) __shared__ unsigned short sWh[3][16384];   // 96 KB
  alignas(16) __shared__ unsigned short sWcomp[16384];   // 32 KB (Wout@Win slice)
  alignas(16) __shared__ unsigned short sWin[4096];      // 8 KB (prologue only)
  __shared__ float sBin[16], sBh[3][16], sBout[16], sBWc[16];
  __shared__ float sDt[128];

  const int bid = blockIdx.x;
  const int g = (bid & 7) >> 1;                 // group 0..3 (XCD pair {2g,2g+1})
  const int j = ((bid >> 3) << 1) | (bid & 1);  // n-slice 0..63
  const int tid = threadIdx.x;
  const int w = tid >> 6;       // wave 0..3 -> 16-row M tile
  const int l = tid & 63;       // lane
  const int lr = l & 15;        // A row / B col / D col
  const int lk = l >> 4;        // k-chunk; D rows = 4*lk + r
  const int rowbase = g * 64 + w * 16;
  unsigned* slots = cnt + g * 64;  // 64 epoch dwords per group (256B)

  // ---- stage sWin, sWh, biases ----
  for (int idx = tid; idx < 256 * 16; idx += 256) {
    int k = idx >> 4, c = idx & 15;
    sWin[((k >> 3) * 16 + c) * 8 + (k & 7)] = f2bf(Win[k * 1024 + j * 16 + c]);
  }
  for (int l3 = 0; l3 < 3; ++l3)
    for (int idx = tid; idx < 1024 * 16; idx += 256) {
      int k = idx >> 4, c = idx & 15;
      sWh[l3][((k >> 3) * 16 + c) * 8 + (k & 7)] =
          f2bf(Wh[(l3 * 1024 + k) * 1024 + j * 16 + c]);
    }
  if (tid < 16) {
    sBin[tid] = bin[j * 16 + tid];
    sBh[0][tid] = bh[j * 16 + tid];
    sBh[1][tid] = bh[1024 + j * 16 + tid];
    sBh[2][tid] = bh[2048 + j * 16 + tid];
    if (j < 16) sBout[tid] = bout[j * 16 + tid];
    float s = 0.f;  // bWc = bout @ Win (own 16 cols)
    for (int xx = 0; xx < 256; ++xx) s += bout[xx] * Win[xx * 1024 + j * 16 + tid];
    sBWc[tid] = s;
  }
  if (tid < 127) sDt[tid] = ts[tid + 1] - ts[tid];
  __syncthreads();

  // ---- one-time: sWcomp = (Wout @ Win)[:, own 16 cols] via MFMA ----
  for (int i = 0; i < 16; ++i) {
    int mt = w * 16 + i;  // 64 m-tiles of 16 rows over the 1024 k-dim
    f32x4 acc = {0.f, 0.f, 0.f, 0.f};
    const float* abase = Wout + (mt * 16 + lr) * 256 + lk * 8;
#pragma unroll
    for (int kk = 0; kk < 8; ++kk) {
      float4 f0 = *(const float4*)(abase + kk * 32);
      float4 f1 = *(const float4*)(abase + kk * 32 + 4);
      short8 a;
      a[0] = (short)f2bf(f0.x); a[1] = (short)f2bf(f0.y);
      a[2] = (short)f2bf(f0.z); a[3] = (short)f2bf(f0.w);
      a[4] = (short)f2bf(f1.x); a[5] = (short)f2bf(f1.y);
      a[6] = (short)f2bf(f1.z); a[7] = (short)f2bf(f1.w);
      short8 b = *(const short8*)(sWin + lk * 128 + lr * 8 + kk * 512);
      acc = __builtin_amdgcn_mfma_f32_16x16x32_bf16(a, b, acc, 0, 0, 0);
    }
#pragma unroll
    for (int r4 = 0; r4 < 4; ++r4) {
      int k = mt * 16 + lk * 4 + r4;
      sWcomp[((k >> 3) * 16 + lr) * 8 + (k & 7)] = f2bf(acc[r4]);
    }
  }

  // Fragment-major panel addressing: base offset for this thread's produced
  // column c (rows vary by lk*4+r4):
  unsigned short* a0g = a0 + (g << 16);
  unsigned short* a1g = a1 + (g << 16);
  const int colH = j * 16 + lr;
  const int pstore = (w << 14) + ((colH >> 5) << 9) + (((colH >> 3) & 3) << 7) +
                     (colH & 7);

  // ---- u0 = x @ Win + bin (fp32 regs); a0 = tanh(u0) ----
  f32x4 u;
  {
    f32x4 acc = {0.f, 0.f, 0.f, 0.f};
    const float* xbase = x + (rowbase + lr) * 256 + lk * 8;
#pragma unroll
    for (int kk = 0; kk < 8; ++kk) {
      float4 f0 = *(const float4*)(xbase + kk * 32);
      float4 f1 = *(const float4*)(xbase + kk * 32 + 4);
      short8 a;
      a[0] = (short)f2bf(f0.x); a[1] = (short)f2bf(f0.y);
      a[2] = (short)f2bf(f0.z); a[3] = (short)f2bf(f0.w);
      a[4] = (short)f2bf(f1.x); a[5] = (short)f2bf(f1.y);
      a[6] = (short)f2bf(f1.z); a[7] = (short)f2bf(f1.w);
      short8 b = *(const short8*)(sWin + lk * 128 + lr * 8 + kk * 512);
      acc = __builtin_amdgcn_mfma_f32_16x16x32_bf16(a, b, acc, 0, 0, 0);
    }
#pragma unroll
    for (int r4 = 0; r4 < 4; ++r4) {
      u[r4] = acc[r4] + sBin[lr];
      AT_ST(&a0g[pstore + ((lk * 4 + r4) << 3)], f2bf(tanhf(u[r4])));
    }
  }

  // ---- j<16: yreg, out[:,0,:], Wout B-fragments into VGPRs ----
  f32x4 yreg = {0.f, 0.f, 0.f, 0.f};
  short8 wfrag[32];
  if (j < 16) {
    for (int idx = tid; idx < 64 * 16; idx += 256) {
      int r = idx >> 4, c = idx & 15;
      int row = g * 64 + r, col = j * 16 + c;
      float v = x[row * 256 + col];
      GST_BYPASS(&out[(row * 128) * 256 + col], v);  // pred[:,0,:] = x
    }
#pragma unroll
    for (int r4 = 0; r4 < 4; ++r4)
      yreg[r4] = x[(rowbase + lk * 4 + r4) * 256 + j * 16 + lr];
#pragma unroll
    for (int kk = 0; kk < 32; ++kk) {
      short8 wv;
#pragma unroll
      for (int d = 0; d < 8; ++d)
        wv[d] = (short)f2bf(Wout[(lk * 8 + kk * 32 + d) * 256 + j * 16 + lr]);
      wfrag[kk] = wv;
    }
  }

  // ---- atomic-free group barrier + acquire-inv (clean L2: inv is cheap) ----
  unsigned bn = 0;
  auto BAR = [&]() {
    ++bn;
    __syncthreads();  // s_waitcnt vmcnt(0): coherent stores are at IF$
    if (tid < 64) {
      if (tid == 0) AT_ST(&slots[j], bn);
      for (;;) {
        unsigned v = AT_LD(&slots[tid]);
        if (__all((int)(v >= bn || tid == (unsigned)j))) break;
        __builtin_amdgcn_s_sleep(1);
      }
    }
    __syncthreads();
    // acquire-only agent fence: buffer_inv (no wbl2). Makes producers'
    // write-through panel stores visible to our subsequent CACHED loads.
    __builtin_amdgcn_fence(__ATOMIC_ACQUIRE, "agent");
  };

  BAR();  // a0 + everything staged, visible group-wide

  for (int t = 0; t < 127; ++t) {
    // ---- Phases B,C,D: h = tanh(h_prev)@Wh[l3] + bh[l3] ----
    for (int l3 = 0; l3 < 3; ++l3) {
      const unsigned short* src = (l3 == 1) ? a1g : a0g;
      unsigned short* dst = (l3 == 1) ? a0g : a1g;
      const unsigned short* pb = src + (w << 14) + (l << 3);
      short8 af[32];
#pragma unroll
      for (int kk = 0; kk < 32; ++kk)
        af[kk] = *(const short8*)(pb + (kk << 9));  // cached: L2-multicast
      f32x4 ac0 = {0.f, 0.f, 0.f, 0.f}, ac1 = {0.f, 0.f, 0.f, 0.f};
#pragma unroll
      for (int kk = 0; kk < 32; kk += 2) {
        short8 b0 = *(const short8*)(sWh[l3] + lk * 128 + lr * 8 + kk * 512);
        short8 b1 = *(const short8*)(sWh[l3] + lk * 128 + lr * 8 + (kk + 1) * 512);
        ac0 = __builtin_amdgcn_mfma_f32_16x16x32_bf16(af[kk], b0, ac0, 0, 0, 0);
        ac1 = __builtin_amdgcn_mfma_f32_16x16x32_bf16(af[kk + 1], b1, ac1, 0, 0, 0);
      }
      f32x4 acc = ac0 + ac1;
      float bias = sBh[l3][lr];
#pragma unroll
      for (int r4 = 0; r4 < 4; ++r4)
        AT_ST(&dst[pstore + ((lk * 4 + r4) << 3)], f2bf(tanhf(acc[r4] + bias)));
      BAR();
    }
    // ---- Phase E': z@Wcomp updates u; j<16 also z@Wout -> y, out ----
    {
      float dt = sDt[t];
      const unsigned short* pb = a1g + (w << 14) + (l << 3);
      short8 af[32];
#pragma unroll
      for (int kk = 0; kk < 32; ++kk)
        af[kk] = *(const short8*)(pb + (kk << 9));  // cached: L2-multicast
      f32x4 ac0 = {0.f, 0.f, 0.f, 0.f}, ac1 = {0.f, 0.f, 0.f, 0.f};
#pragma unroll
      for (int kk = 0; kk < 32; kk += 2) {
        short8 b0 = *(const short8*)(sWcomp + lk * 128 + lr * 8 + kk * 512);
        short8 b1 = *(const short8*)(sWcomp + lk * 128 + lr * 8 + (kk + 1) * 512);
        ac0 = __builtin_amdgcn_mfma_f32_16x16x32_bf16(af[kk], b0, ac0, 0, 0, 0);
        ac1 = __builtin_amdgcn_mfma_f32_16x16x32_bf16(af[kk + 1], b1, ac1, 0, 0, 0);
      }
      f32x4 accC = ac0 + ac1;
#pragma unroll
      for (int r4 = 0; r4 < 4; ++r4) {
        u[r4] += dt * (accC[r4] + sBWc[lr]);
        AT_ST(&a0g[pstore + ((lk * 4 + r4) << 3)], f2bf(tanhf(u[r4])));
      }
      if (j < 16) {
        f32x4 accO = {0.f, 0.f, 0.f, 0.f};
#pragma unroll
        for (int kk = 0; kk < 32; ++kk)
          accO = __builtin_amdgcn_mfma_f32_16x16x32_bf16(af[kk], wfrag[kk],
                                                         accO, 0, 0, 0);
#pragma unroll
        for (int r4 = 0; r4 < 4; ++r4) {
          float yv = yreg[r4] + dt * (accO[r4] + sBout[lr]);
          yreg[r4] = yv;
          int row = rowbase + lk * 4 + r4;
          GST_BYPASS(&out[(row * 128 + t + 1) * 256 + j * 16 + lr], yv);
        }
      }
      BAR();
    }
  }
}

extern "C" void kernel_launch(void* const* d_in, const int* in_sizes, int n_in,
                              void* d_out, int out_size, void* d_ws, size_t ws_size,
                              hipStream_t stream) {
  (void)in_sizes; (void)n_in; (void)out_size; (void)ws_size;
  const float* x    = (const float*)d_in[0];
  const float* ts   = (const float*)d_in[1];
  const float* Win  = (const float*)d_in[2];
  const float* bin  = (const float*)d_in[3];
  const float* Wh   = (const float*)d_in[4];
  const float* bh   = (const float*)d_in[5];
  const float* Wout = (const float*)d_in[6];
  const float* bout = (const float*)d_in[7];
  float* out = (float*)d_out;

  char* ws = (char*)d_ws;
  unsigned* cnt = (unsigned*)ws;                               // 4 KB epoch slots
  unsigned short* a0 = (unsigned short*)(ws + 4096);           // 512 KB
  unsigned short* a1 = (unsigned short*)(ws + 4096 + 524288);  // 512 KB

  hipMemsetAsync(ws, 0, 4096, stream);  // zero epoch slots each call

  // Persistent spin-barrier kernel: co-residency of all 256 blocks required.
  void* args[] = {(void*)&x,    (void*)&ts,  (void*)&Win,  (void*)&bin,
                  (void*)&Wh,   (void*)&bh,  (void*)&Wout, (void*)&bout,
                  (void*)&out,  (void*)&cnt, (void*)&a0,   (void*)&a1};
  hipError_t e = hipLaunchCooperativeKernel((const void*)node_persistent,
                                            dim3(256), dim3(256), args, 0, stream);
  if (e != hipSuccess) {
    hipLaunchKernelGGL(node_persistent, dim3(256), dim3(256), 0, stream,
                       x, ts, Win, bin, Wh, bh, Wout, bout, out, cnt, a0, a1);
  }
}

// Round 12
// 4590.402 us; speedup vs baseline: 1.3751x; 1.3751x over previous
//
#include <hip/hip_runtime.h>
#include <hip/hip_bf16.h>

// Neural ODE Euler rollout. Round-12: hang-proofed three-way diagnostic.
//  - v2 (k-split, S=4): R7 structure + R5's verified full-K y-path. Barriers
//    now have a bounded-spin escape (s_dead): a deadlock terminates quickly
//    with wrong output instead of hanging the GPU (suspected cause of the
//    R10/R11 container failures).
//  - v1 (R5 verbatim, verified 3081us/0.03125): launched when ws_size too
//    small for v2 (tests the R7/R8 workspace-overflow hypothesis).
// All cross-block traffic: coherent sc0 sc1 bypass (IF$); no fences in loop.

typedef __attribute__((ext_vector_type(8))) short short8;
typedef __attribute__((ext_vector_type(4))) float f32x4;

#define AT_LD(p) __hip_atomic_load((p), __ATOMIC_RELAXED, __HIP_MEMORY_SCOPE_AGENT)
#define AT_ST(p, v) \
  __hip_atomic_store((p), (v), __ATOMIC_RELAXED, __HIP_MEMORY_SCOPE_AGENT)

#define GLDX4(dst, ptr) \
  asm volatile("global_load_dwordx4 %0, %1, off sc0 sc1" \
               : "=v"(dst) : "v"(ptr) : "memory")
#define GSTX4(ptr, val) \
  asm volatile("global_store_dwordx4 %0, %1, off sc0 sc1" \
               :: "v"(ptr), "v"(val) : "memory")
#define VM_WAIT0()                                   \
  do {                                               \
    asm volatile("s_waitcnt vmcnt(0)" ::: "memory"); \
    __builtin_amdgcn_sched_barrier(0);               \
  } while (0)

#define MFMA __builtin_amdgcn_mfma_f32_16x16x32_bf16

__device__ inline unsigned short f2bf(float f) {
  unsigned u = __builtin_bit_cast(unsigned, f);
  unsigned r = u + 0x7FFFu + ((u >> 16) & 1u);
  return (unsigned short)(r >> 16);
}

// ===================== v2: k-split (S=4) + R5 y-path, hang-proof =====================
__global__ __launch_bounds__(256, 1) void node_ksplit(
    const float* __restrict__ x, const float* __restrict__ ts,
    const float* __restrict__ Win, const float* __restrict__ bin,
    const float* __restrict__ Wh, const float* __restrict__ bh,
    const float* __restrict__ Wout, const float* __restrict__ bout,
    float* __restrict__ out,
    unsigned* __restrict__ gslots, unsigned* __restrict__ sub,
    float* __restrict__ pz,
    unsigned short* __restrict__ a0, unsigned short* __restrict__ a1) {
  alignas(16) __shared__ unsigned short sWh[3][16384];  // 96 KB
  alignas(16) __shared__ unsigned short sWcomp[16384];  // 32 KB (Wout@Win slice)
  __shared__ float sBh[3][16], sBWc[16], sBout[16], sDt[128];
  __shared__ int s_dead;

  const int bid = blockIdx.x;
  const int g = bid >> 6;
  const int loc = bid & 63;
  const int s = loc >> 4;        // k-slice 0..3
  const int n = loc & 15;        // 64-col H family 0..15
  const int cg = n * 4 + s;      // owned 16-col output granule
  const int tid = threadIdx.x;
  const int w = tid >> 6;
  const int l = tid & 63;
  const int lr = l & 15;
  const int lk = l >> 4;
  unsigned* myg = gslots + g * 64;
  unsigned* mysub = sub + (g * 16 + n) * 4;

  if (tid == 0) s_dead = 0;

  // ---- (1) WinT temp (256 x 64 n-cols) into sWh[2] ----
  unsigned short* wt = sWh[2];
  for (int idx = tid; idx < 256 * 64; idx += 256) {
    int k = idx >> 6, c = idx & 63;
    wt[((k >> 3) * 64 + c) * 8 + (k & 7)] = f2bf(Win[k * 1024 + n * 64 + c]);
  }
  __syncthreads();

  // ---- (2a) u0 = x@Win + bin for own cg cols ----
  f32x4 u;
  {
    f32x4 acc = {0.f, 0.f, 0.f, 0.f};
    const float* xb = x + (g * 64 + w * 16 + lr) * 256 + lk * 8;
#pragma unroll
    for (int kk = 0; kk < 8; ++kk) {
      short8 a;
#pragma unroll
      for (int d = 0; d < 8; ++d) a[d] = (short)f2bf(xb[kk * 32 + d]);
      short8 b = *(const short8*)(wt + kk * 2048 + lk * 512 + s * 128 + lr * 8);
      acc = MFMA(a, b, acc, 0, 0, 0);
    }
#pragma unroll
    for (int r4 = 0; r4 < 4; ++r4) u[r4] = acc[r4] + bin[cg * 16 + lr];
  }

  // ---- (2b) Wcomp = (Wout@Win) slice rows [s*256,+256), cols [n*64,+64) ----
  for (int i = 0; i < 4; ++i) {
    int mt = w * 4 + i;
    f32x4 c0 = {0,0,0,0}, c1 = {0,0,0,0}, c2 = {0,0,0,0}, c3 = {0,0,0,0};
    const float* ab = Wout + (s * 256 + mt * 16 + lr) * 256 + lk * 8;
#pragma unroll
    for (int kk = 0; kk < 8; ++kk) {
      short8 a;
#pragma unroll
      for (int d = 0; d < 8; ++d) a[d] = (short)f2bf(ab[kk * 32 + d]);
      const unsigned short* bb = wt + kk * 2048 + lk * 512 + lr * 8;
      c0 = MFMA(a, *(const short8*)(bb + 0),   c0, 0, 0, 0);
      c1 = MFMA(a, *(const short8*)(bb + 128), c1, 0, 0, 0);
      c2 = MFMA(a, *(const short8*)(bb + 256), c2, 0, 0, 0);
      c3 = MFMA(a, *(const short8*)(bb + 384), c3, 0, 0, 0);
    }
    auto stc = [&](int nt, f32x4 a) {
#pragma unroll
      for (int r4 = 0; r4 < 4; ++r4) {
        int kl = mt * 16 + lk * 4 + r4, cl = nt * 16 + lr;
        sWcomp[((kl >> 3) * 64 + cl) * 8 + (kl & 7)] = f2bf(a[r4]);
      }
    };
    stc(0, c0); stc(1, c1); stc(2, c2); stc(3, c3);
  }
  __syncthreads();  // done with WinT temp

  // ---- (3) stage Wh slices + biases ----
  for (int m = 0; m < 3; ++m)
    for (int idx = tid; idx < 256 * 64; idx += 256) {
      int k = idx >> 6, c = idx & 63;
      sWh[m][((k >> 3) * 64 + c) * 8 + (k & 7)] =
          f2bf(Wh[(m * 1024 + s * 256 + k) * 1024 + n * 64 + c]);
    }
  if (tid < 16) {
    sBh[0][tid] = bh[cg * 16 + tid];
    sBh[1][tid] = bh[1024 + cg * 16 + tid];
    sBh[2][tid] = bh[2048 + cg * 16 + tid];
    sBout[tid] = bout[n * 16 + tid];
    float sum = 0.f;
    for (int xx = 0; xx < 256; ++xx)
      sum += bout[xx] * Win[xx * 1024 + cg * 16 + tid];
    sBWc[tid] = sum;
  }
  if (tid < 127) sDt[tid] = ts[tid + 1] - ts[tid];

  // ---- publish a0 = tanh(u0) ----
  unsigned short* a0g = a0 + (g << 16);
  unsigned short* a1g = a1 + (g << 16);
  const int ccol = cg * 16 + lr;
  const int pcol = ((ccol >> 5) << 9) + (((ccol >> 3) & 3) << 7) + (ccol & 7);
#pragma unroll
  for (int r4 = 0; r4 < 4; ++r4)
    AT_ST(&a0g[(w << 14) + pcol + ((lk * 4 + r4) << 3)], f2bf(tanhf(u[r4])));

  // ---- y-path (R5-verified): s==0 blocks, full-K Wout fragments in VGPRs ----
  f32x4 yreg = {0.f, 0.f, 0.f, 0.f};
  short8 wfrag[32];
  if (s == 0) {
    for (int idx = tid; idx < 64 * 16; idx += 256) {
      int r = idx >> 4, c = idx & 15;
      out[((g * 64 + r) * 128) * 256 + n * 16 + c] =
          x[(g * 64 + r) * 256 + n * 16 + c];  // pred[:,0,:] = x
    }
#pragma unroll
    for (int r4 = 0; r4 < 4; ++r4)
      yreg[r4] = x[(g * 64 + w * 16 + lk * 4 + r4) * 256 + n * 16 + lr];
#pragma unroll
    for (int kk = 0; kk < 32; ++kk) {
      short8 wv;
#pragma unroll
      for (int d = 0; d < 8; ++d)
        wv[d] = (short)f2bf(Wout[(lk * 8 + kk * 32 + d) * 256 + n * 16 + lr]);
      wfrag[kk] = wv;
    }
  }

  unsigned ph = 0;
  // Bounded-spin barriers: on timeout, set s_dead and stop synchronizing.
  // Wrong output then, but the kernel TERMINATES (no GPU hang). Spin counter
  // is lane-uniform -> all lanes exit the loop together.
  auto BAR = [&]() {
    VM_WAIT0();
    __syncthreads();
    if (!s_dead) {
      if (tid < 64) {
        if (tid == 0) AT_ST(&myg[loc], ph);
        int it = 0;
        for (;;) {
          unsigned v = AT_LD(&myg[tid]);
          if (__all((int)(v >= ph || tid == loc))) break;
          if (++it > (1 << 20)) { if (tid == 0) s_dead = 1; break; }
          __builtin_amdgcn_s_sleep(1);
        }
      }
    }
    __syncthreads();
  };
  auto SUBBAR = [&]() {
    VM_WAIT0();
    __syncthreads();
    if (!s_dead) {
      if (tid < 4) {
        if (tid == 0) AT_ST(&mysub[s], ph);
        int it = 0;
        for (;;) {
          unsigned v = AT_LD(&mysub[tid]);
          if (__all((int)(v >= ph || tid == s))) break;
          if (++it > (1 << 20)) { if (tid == 0) s_dead = 1; break; }
          __builtin_amdgcn_s_sleep(1);
        }
      }
    }
    __syncthreads();
  };

  ++ph;
  BAR();

  const int toff = lr * 64 + w * 16 + lk * 4;  // [col16][row64] f32 tile index
  float* pzb = pz + ((g * 16 + n) << 14);

  for (int t = 0; t < 127; ++t) {
    // ---- layers 1..3 (k-split + sub-barrier reduction) ----
    for (int l3 = 0; l3 < 3; ++l3) {
      const unsigned short* src = (l3 & 1) ? a1g : a0g;
      unsigned short* dst = (l3 & 1) ? a0g : a1g;
      ++ph;
      const unsigned short* pb = src + (w << 14) + (s << 12) + (l << 3);
      short8 af[8];
#pragma unroll
      for (int kk = 0; kk < 8; ++kk) GLDX4(af[kk], pb + (kk << 9));
      VM_WAIT0();
      f32x4 q0 = {0,0,0,0}, q1 = {0,0,0,0}, q2 = {0,0,0,0}, q3 = {0,0,0,0};
#pragma unroll
      for (int kk = 0; kk < 8; ++kk) {
        const unsigned short* bb = sWh[l3] + kk * 2048 + lk * 512 + lr * 8;
        q0 = MFMA(af[kk], *(const short8*)(bb + 0),   q0, 0, 0, 0);
        q1 = MFMA(af[kk], *(const short8*)(bb + 128), q1, 0, 0, 0);
        q2 = MFMA(af[kk], *(const short8*)(bb + 256), q2, 0, 0, 0);
        q3 = MFMA(af[kk], *(const short8*)(bb + 384), q3, 0, 0, 0);
      }
      float* sbase = pzb + (s << 12) + toff;
      if (s != 0) GSTX4(sbase + 0 * 1024, q0);
      if (s != 1) GSTX4(sbase + 1 * 1024, q1);
      if (s != 2) GSTX4(sbase + 2 * 1024, q2);
      if (s != 3) GSTX4(sbase + 3 * 1024, q3);
      SUBBAR();
      f32x4 own = (s == 0) ? q0 : (s == 1) ? q1 : (s == 2) ? q2 : q3;
      const float* rb = pzb + (s << 10) + toff;
      f32x4 r0 = {0,0,0,0}, r1 = {0,0,0,0}, r2 = {0,0,0,0}, r3 = {0,0,0,0};
      if (s != 0) GLDX4(r0, rb + (0 << 12));
      if (s != 1) GLDX4(r1, rb + (1 << 12));
      if (s != 2) GLDX4(r2, rb + (2 << 12));
      if (s != 3) GLDX4(r3, rb + (3 << 12));
      VM_WAIT0();
      f32x4 sum = r0 + r1 + r2 + r3 + own;
      float bias = sBh[l3][lr];
#pragma unroll
      for (int r4 = 0; r4 < 4; ++r4)
        AT_ST(&dst[(w << 14) + pcol + ((lk * 4 + r4) << 3)],
              f2bf(tanhf(sum[r4] + bias)));
      BAR();
    }
    // ---- E': u via k-split Wcomp; y via R5 full-K path (s==0 only) ----
    {
      ++ph;
      float dt = sDt[t];
      short8 af[32];
      f32x4 accO = {0.f, 0.f, 0.f, 0.f};
      if (s == 0) {
        const unsigned short* pbf = a1g + (w << 14) + (l << 3);
#pragma unroll
        for (int kk = 0; kk < 32; ++kk) GLDX4(af[kk], pbf + (kk << 9));
        VM_WAIT0();
#pragma unroll
        for (int kk = 0; kk < 32; ++kk)
          accO = MFMA(af[kk], wfrag[kk], accO, 0, 0, 0);
      } else {
        const unsigned short* pb = a1g + (w << 14) + (s << 12) + (l << 3);
#pragma unroll
        for (int kk = 0; kk < 8; ++kk) GLDX4(af[kk], pb + (kk << 9));
        VM_WAIT0();
      }
      f32x4 q0 = {0,0,0,0}, q1 = {0,0,0,0}, q2 = {0,0,0,0}, q3 = {0,0,0,0};
#pragma unroll
      for (int kk = 0; kk < 8; ++kk) {
        const unsigned short* bb = sWcomp + kk * 2048 + lk * 512 + lr * 8;
        q0 = MFMA(af[kk], *(const short8*)(bb + 0),   q0, 0, 0, 0);
        q1 = MFMA(af[kk], *(const short8*)(bb + 128), q1, 0, 0, 0);
        q2 = MFMA(af[kk], *(const short8*)(bb + 256), q2, 0, 0, 0);
        q3 = MFMA(af[kk], *(const short8*)(bb + 384), q3, 0, 0, 0);
      }
      float* sbase = pzb + (s << 12) + toff;
      if (s != 0) GSTX4(sbase + 0 * 1024, q0);
      if (s != 1) GSTX4(sbase + 1 * 1024, q1);
      if (s != 2) GSTX4(sbase + 2 * 1024, q2);
      if (s != 3) GSTX4(sbase + 3 * 1024, q3);
      SUBBAR();
      f32x4 own = (s == 0) ? q0 : (s == 1) ? q1 : (s == 2) ? q2 : q3;
      const float* rb = pzb + (s << 10) + toff;
      f32x4 r0 = {0,0,0,0}, r1 = {0,0,0,0}, r2 = {0,0,0,0}, r3 = {0,0,0,0};
      if (s != 0) GLDX4(r0, rb + (0 << 12));
      if (s != 1) GLDX4(r1, rb + (1 << 12));
      if (s != 2) GLDX4(r2, rb + (2 << 12));
      if (s != 3) GLDX4(r3, rb + (3 << 12));
      VM_WAIT0();
      f32x4 sum = r0 + r1 + r2 + r3 + own;
#pragma unroll
      for (int r4 = 0; r4 < 4; ++r4) {
        u[r4] += dt * (sum[r4] + sBWc[lr]);
        AT_ST(&a0g[(w << 14) + pcol + ((lk * 4 + r4) << 3)],
              f2bf(tanhf(u[r4])));
      }
      if (s == 0) {
#pragma unroll
        for (int r4 = 0; r4 < 4; ++r4) {
          float yv = yreg[r4] + dt * (accO[r4] + sBout[lr]);
          yreg[r4] = yv;
          out[((g * 64 + w * 16 + lk * 4 + r4) * 128 + t + 1) * 256 + n * 16 +
              lr] = yv;
        }
      }
      BAR();
    }
  }
}

// ===================== v1: Round-5 kernel VERBATIM (verified) =====================
__global__ __launch_bounds__(256, 1) void node_r5(
    const float* __restrict__ x, const float* __restrict__ ts,
    const float* __restrict__ Win, const float* __restrict__ bin,
    const float* __restrict__ Wh, const float* __restrict__ bh,
    const float* __restrict__ Wout, const float* __restrict__ bout,
    float* __restrict__ out,
    unsigned* __restrict__ cnt,
    unsigned short* __restrict__ a0,
    unsigned short* __restrict__ a1) {
  alignas(16) __shared__ unsigned short sWh[3][16384];
  alignas(16) __shared__ unsigned short sWcomp[16384];
  alignas(16) __shared__ unsigned short sWin[4096];
  __shared__ float sBin[16], sBh[3][16], sBout[16], sBWc[16];
  __shared__ float sDt[128];

  const int bid = blockIdx.x;
  const int g = (bid & 7) >> 1;
  const int j = ((bid >> 3) << 1) | (bid & 1);
  const int tid = threadIdx.x;
  const int w = tid >> 6;
  const int l = tid & 63;
  const int lr = l & 15;
  const int lk = l >> 4;
  const int rowbase = g * 64 + w * 16;
  unsigned* slots = cnt + g * 64;

  for (int idx = tid; idx < 256 * 16; idx += 256) {
    int k = idx >> 4, c = idx & 15;
    sWin[((k >> 3) * 16 + c) * 8 + (k & 7)] = f2bf(Win[k * 1024 + j * 16 + c]);
  }
  for (int l3 = 0; l3 < 3; ++l3)
    for (int idx = tid; idx < 1024 * 16; idx += 256) {
      int k = idx >> 4, c = idx & 15;
      sWh[l3][((k >> 3) * 16 + c) * 8 + (k & 7)] =
          f2bf(Wh[(l3 * 1024 + k) * 1024 + j * 16 + c]);
    }
  if (tid < 16) {
    sBin[tid] = bin[j * 16 + tid];
    sBh[0][tid] = bh[j * 16 + tid];
    sBh[1][tid] = bh[1024 + j * 16 + tid];
    sBh[2][tid] = bh[2048 + j * 16 + tid];
    if (j < 16) sBout[tid] = bout[j * 16 + tid];
    float s = 0.f;
    for (int xx = 0; xx < 256; ++xx) s += bout[xx] * Win[xx * 1024 + j * 16 + tid];
    sBWc[tid] = s;
  }
  if (tid < 127) sDt[tid] = ts[tid + 1] - ts[tid];
  __syncthreads();

  for (int i = 0; i < 16; ++i) {
    int mt = w * 16 + i;
    f32x4 acc = {0.f, 0.f, 0.f, 0.f};
    const float* abase = Wout + (mt * 16 + lr) * 256 + lk * 8;
#pragma unroll
    for (int kk = 0; kk < 8; ++kk) {
      float4 f0 = *(const float4*)(abase + kk * 32);
      float4 f1 = *(const float4*)(abase + kk * 32 + 4);
      short8 a;
      a[0] = (short)f2bf(f0.x); a[1] = (short)f2bf(f0.y);
      a[2] = (short)f2bf(f0.z); a[3] = (short)f2bf(f0.w);
      a[4] = (short)f2bf(f1.x); a[5] = (short)f2bf(f1.y);
      a[6] = (short)f2bf(f1.z); a[7] = (short)f2bf(f1.w);
      short8 b = *(const short8*)(sWin + lk * 128 + lr * 8 + kk * 512);
      acc = MFMA(a, b, acc, 0, 0, 0);
    }
#pragma unroll
    for (int r4 = 0; r4 < 4; ++r4) {
      int k = mt * 16 + lk * 4 + r4;
      sWcomp[((k >> 3) * 16 + lr) * 8 + (k & 7)] = f2bf(acc[r4]);
    }
  }

  unsigned short* a0g = a0 + (g << 16);
  unsigned short* a1g = a1 + (g << 16);
  const int colH = j * 16 + lr;
  const int pstore = (w << 14) + ((colH >> 5) << 9) + (((colH >> 3) & 3) << 7) +
                     (colH & 7);

  f32x4 u;
  {
    f32x4 acc = {0.f, 0.f, 0.f, 0.f};
    const float* xbase = x + (rowbase + lr) * 256 + lk * 8;
#pragma unroll
    for (int kk = 0; kk < 8; ++kk) {
      float4 f0 = *(const float4*)(xbase + kk * 32);
      float4 f1 = *(const float4*)(xbase + kk * 32 + 4);
      short8 a;
      a[0] = (short)f2bf(f0.x); a[1] = (short)f2bf(f0.y);
      a[2] = (short)f2bf(f0.z); a[3] = (short)f2bf(f0.w);
      a[4] = (short)f2bf(f1.x); a[5] = (short)f2bf(f1.y);
      a[6] = (short)f2bf(f1.z); a[7] = (short)f2bf(f1.w);
      short8 b = *(const short8*)(sWin + lk * 128 + lr * 8 + kk * 512);
      acc = MFMA(a, b, acc, 0, 0, 0);
    }
#pragma unroll
    for (int r4 = 0; r4 < 4; ++r4) {
      u[r4] = acc[r4] + sBin[lr];
      AT_ST(&a0g[pstore + ((lk * 4 + r4) << 3)], f2bf(tanhf(u[r4])));
    }
  }

  f32x4 yreg = {0.f, 0.f, 0.f, 0.f};
  short8 wfrag[32];
  if (j < 16) {
    for (int idx = tid; idx < 64 * 16; idx += 256) {
      int r = idx >> 4, c = idx & 15;
      int row = g * 64 + r, col = j * 16 + c;
      out[(row * 128) * 256 + col] = x[row * 256 + col];
    }
#pragma unroll
    for (int r4 = 0; r4 < 4; ++r4)
      yreg[r4] = x[(rowbase + lk * 4 + r4) * 256 + j * 16 + lr];
#pragma unroll
    for (int kk = 0; kk < 32; ++kk) {
      short8 wv;
#pragma unroll
      for (int d = 0; d < 8; ++d)
        wv[d] = (short)f2bf(Wout[(lk * 8 + kk * 32 + d) * 256 + j * 16 + lr]);
      wfrag[kk] = wv;
    }
  }

  unsigned bn = 0;
  auto BAR = [&]() {
    ++bn;
    __syncthreads();
    if (tid < 64) {
      if (tid == 0) AT_ST(&slots[j], bn);
      for (;;) {
        unsigned v = AT_LD(&slots[tid]);
        if (__all((int)(v >= bn || tid == (unsigned)j))) break;
        __builtin_amdgcn_s_sleep(1);
      }
    }
    __syncthreads();
  };

  BAR();

  for (int t = 0; t < 127; ++t) {
    for (int l3 = 0; l3 < 3; ++l3) {
      const unsigned short* src = (l3 == 1) ? a1g : a0g;
      unsigned short* dst = (l3 == 1) ? a0g : a1g;
      const unsigned short* pb = src + (w << 14) + (l << 3);
      short8 af[32];
#pragma unroll
      for (int kk = 0; kk < 32; ++kk) GLDX4(af[kk], pb + (kk << 9));
      VM_WAIT0();
      f32x4 ac0 = {0.f, 0.f, 0.f, 0.f}, ac1 = {0.f, 0.f, 0.f, 0.f};
#pragma unroll
      for (int kk = 0; kk < 32; kk += 2) {
        short8 b0 = *(const short8*)(sWh[l3] + lk * 128 + lr * 8 + kk * 512);
        short8 b1 = *(const short8*)(sWh[l3] + lk * 128 + lr * 8 + (kk + 1) * 512);
        ac0 = MFMA(af[kk], b0, ac0, 0, 0, 0);
        ac1 = MFMA(af[kk + 1], b1, ac1, 0, 0, 0);
      }
      f32x4 acc = ac0 + ac1;
      float bias = sBh[l3][lr];
#pragma unroll
      for (int r4 = 0; r4 < 4; ++r4)
        AT_ST(&dst[pstore + ((lk * 4 + r4) << 3)], f2bf(tanhf(acc[r4] + bias)));
      BAR();
    }
    {
      float dt = sDt[t];
      const unsigned short* pb = a1g + (w << 14) + (l << 3);
      short8 af[32];
#pragma unroll
      for (int kk = 0; kk < 32; ++kk) GLDX4(af[kk], pb + (kk << 9));
      VM_WAIT0();
      f32x4 ac0 = {0.f, 0.f, 0.f, 0.f}, ac1 = {0.f, 0.f, 0.f, 0.f};
#pragma unroll
      for (int kk = 0; kk < 32; kk += 2) {
        short8 b0 = *(const short8*)(sWcomp + lk * 128 + lr * 8 + kk * 512);
        short8 b1 = *(const short8*)(sWcomp + lk * 128 + lr * 8 + (kk + 1) * 512);
        ac0 = MFMA(af[kk], b0, ac0, 0, 0, 0);
        ac1 = MFMA(af[kk + 1], b1, ac1, 0, 0, 0);
      }
      f32x4 accC = ac0 + ac1;
#pragma unroll
      for (int r4 = 0; r4 < 4; ++r4) {
        u[r4] += dt * (accC[r4] + sBWc[lr]);
        AT_ST(&a0g[pstore + ((lk * 4 + r4) << 3)], f2bf(tanhf(u[r4])));
      }
      if (j < 16) {
        f32x4 accO = {0.f, 0.f, 0.f, 0.f};
#pragma unroll
        for (int kk = 0; kk < 32; ++kk)
          accO = MFMA(af[kk], wfrag[kk], accO, 0, 0, 0);
#pragma unroll
        for (int r4 = 0; r4 < 4; ++r4) {
          float yv = yreg[r4] + dt * (accO[r4] + sBout[lr]);
          yreg[r4] = yv;
          int row = rowbase + lk * 4 + r4;
          out[(row * 128 + t + 1) * 256 + j * 16 + lr] = yv;
        }
      }
      BAR();
    }
  }
}

extern "C" void kernel_launch(void* const* d_in, const int* in_sizes, int n_in,
                              void* d_out, int out_size, void* d_ws, size_t ws_size,
                              hipStream_t stream) {
  (void)in_sizes; (void)n_in; (void)out_size;
  const float* x    = (const float*)d_in[0];
  const float* ts   = (const float*)d_in[1];
  const float* Win  = (const float*)d_in[2];
  const float* bin  = (const float*)d_in[3];
  const float* Wh   = (const float*)d_in[4];
  const float* bh   = (const float*)d_in[5];
  const float* Wout = (const float*)d_in[6];
  const float* bout = (const float*)d_in[7];
  float* out = (float*)d_out;

  char* ws = (char*)d_ws;
  unsigned* gslots = (unsigned*)ws;                             // 1 KB
  unsigned* sub    = (unsigned*)(ws + 2048);                    // 1 KB
  unsigned short* a0 = (unsigned short*)(ws + 4096);            // 512 KB
  unsigned short* a1 = (unsigned short*)(ws + 4096 + 524288);   // 512 KB
  float* pz = (float*)(ws + 4096 + 1048576);                    // 4 MB (v2 only)

  hipMemsetAsync(ws, 0, 4096, stream);

  const size_t need_v2 = 4096 + 1048576 + 4194304;  // 5.25 MB
  if (ws_size >= need_v2 + (1 << 20)) {  // 1 MB margin
    void* args[] = {(void*)&x,   (void*)&ts,     (void*)&Win,  (void*)&bin,
                    (void*)&Wh,  (void*)&bh,     (void*)&Wout, (void*)&bout,
                    (void*)&out, (void*)&gslots, (void*)&sub,  (void*)&pz,
                    (void*)&a0,  (void*)&a1};
    hipError_t e = hipLaunchCooperativeKernel((const void*)node_ksplit,
                                              dim3(256), dim3(256), args, 0,
                                              stream);
    if (e != hipSuccess) {
      hipLaunchKernelGGL(node_ksplit, dim3(256), dim3(256), 0, stream,
                         x, ts, Win, bin, Wh, bh, Wout, bout, out, gslots, sub,
                         pz, a0, a1);
    }
  } else {
    void* args[] = {(void*)&x,    (void*)&ts,     (void*)&Win,  (void*)&bin,
                    (void*)&Wh,   (void*)&bh,     (void*)&Wout, (void*)&bout,
                    (void*)&out,  (void*)&gslots, (void*)&a0,   (void*)&a1};
    hipError_t e = hipLaunchCooperativeKernel((const void*)node_r5,
                                              dim3(256), dim3(256), args, 0,
                                              stream);
    if (e != hipSuccess) {
      hipLaunchKernelGGL(node_r5, dim3(256), dim3(256), 0, stream,
                         x, ts, Win, bin, Wh, bh, Wout, bout, out, gslots, a0,
                         a1);
    }
  }
}